// Round 1
// 371.681 us; speedup vs baseline: 1.0163x; 1.0163x over previous
//
#include <hip/hip_runtime.h>
#include <stdint.h>

// Problem constants
#define B_   4
#define S_   2048
#define H_   16
#define D_   64
#define DM_  1024
#define NTOK (B_ * S_)          // 8192 tokens

typedef __attribute__((ext_vector_type(8))) short short8;   // 8 bf16 (4 VGPRs)
typedef __attribute__((ext_vector_type(4))) float floatx4;  // MFMA C/D

__device__ inline unsigned short f2bf(float f) {
  // RNE float -> bf16 (finite inputs)
  unsigned int u = __float_as_uint(f);
  u += 0x7FFFu + ((u >> 16) & 1u);
  return (unsigned short)(u >> 16);
}

__device__ inline floatx4 mfma_bf16(short8 a, short8 b, floatx4 c) {
  return __builtin_amdgcn_mfma_f32_16x16x32_bf16(a, b, c, 0, 0, 0);
}

// pack two fp32 into bf16x2 (RTZ: take high 16 bits of each) — one v_perm_b32
__device__ inline unsigned int pack_bf2(float lo, float hi) {
  return __builtin_amdgcn_perm(__float_as_uint(hi), __float_as_uint(lo), 0x07060302u);
}

// async global->LDS, 16B per lane; LDS dest = wave-uniform base + lane*16
__device__ inline void gload_lds16(const unsigned short* g, unsigned short* l) {
  __builtin_amdgcn_global_load_lds(
      (const __attribute__((address_space(1))) unsigned int*)g,
      (__attribute__((address_space(3))) unsigned int*)l, 16, 0, 0);
}

// ---------------------------------------------------------------------------
// fp32 -> bf16 bulk cast
// ---------------------------------------------------------------------------
__global__ __launch_bounds__(256) void cast_bf16_kernel(const float* __restrict__ in,
                                                        unsigned short* __restrict__ out,
                                                        int n4) {
  int i = blockIdx.x * 256 + threadIdx.x;
  if (i < n4) {
    float4 v = ((const float4*)in)[i];
    ushort4 o;
    o.x = f2bf(v.x); o.y = f2bf(v.y); o.z = f2bf(v.z); o.w = f2bf(v.w);
    ((ushort4*)out)[i] = o;
  }
}

// ---------------------------------------------------------------------------
// LDS-tiled weight cast+transpose: w[k][n] fp32 [1024x1024] -> wT[n][k] bf16.
// 64x64 tiles; coalesced fp32 reads, coalesced short8 writes. z selects
// which of the 4 weights (one launch for all).
// ---------------------------------------------------------------------------
__global__ __launch_bounds__(256) void wt_kernel(const float* __restrict__ w0,
                                                 const float* __restrict__ w1,
                                                 const float* __restrict__ w2,
                                                 const float* __restrict__ w3,
                                                 unsigned short* __restrict__ o0,
                                                 unsigned short* __restrict__ o1,
                                                 unsigned short* __restrict__ o2,
                                                 unsigned short* __restrict__ o3) {
  __shared__ unsigned short T[64 * 68];   // transposed tile [n][k], stride 68
  const float* w = blockIdx.z == 0 ? w0 : blockIdx.z == 1 ? w1 : blockIdx.z == 2 ? w2 : w3;
  unsigned short* o = blockIdx.z == 0 ? o0 : blockIdx.z == 1 ? o1 : blockIdx.z == 2 ? o2 : o3;
  const int tid = threadIdx.x;
  const int R0 = blockIdx.y * 64;   // k-block
  const int C0 = blockIdx.x * 64;   // n-block
  for (int it = 0; it < 16; it++) {
    int lr = it * 4 + (tid >> 6), lc = tid & 63;
    T[lc * 68 + lr] = f2bf(w[(size_t)(R0 + lr) * 1024 + C0 + lc]);
  }
  __syncthreads();
  for (int it = 0; it < 2; it++) {
    int orow = it * 32 + (tid >> 3), oc = (tid & 7) * 8;
    union { ushort4 h[2]; short8 v8; } u;
    u.h[0] = *(const ushort4*)(T + orow * 68 + oc);
    u.h[1] = *(const ushort4*)(T + orow * 68 + oc + 4);
    *(short8*)(o + (size_t)(C0 + orow) * 1024 + R0 + oc) = u.v8;
  }
}

// ---------------------------------------------------------------------------
// bf16 GEMM (m97 structure): C[8192,1024] = A[8192,1024] x BT[1024,1024]^T
// MODE 0: scale + bf16 scatter into [B,H,S,64]
// MODE 1: fp32 row-major
// MODE 2: bf16 scatter into V^T layout [B,H,64,S] with per-64-block sigma
//         permutation of s (p = inv_sigma(s&63) = ((s&63)>>4) + (s&15)*4)
// ---------------------------------------------------------------------------
template <int MODE>
__global__ __launch_bounds__(256) void gemm_bt_kernel(const unsigned short* __restrict__ A,
                                                      const unsigned short* __restrict__ BT,
                                                      void* __restrict__ Cout,
                                                      float scale) {
  constexpr int K = 1024;
  __shared__ unsigned short As[128 * 32];  // 8 KB, slot i (16B) = chunk i row-major
  __shared__ unsigned short Bs[128 * 32];  // 8 KB

  const int tid  = threadIdx.x;
  const int wave = tid >> 6, lane = tid & 63;
  const int quad = lane >> 4, l16 = lane & 15;
  const int wm = wave >> 1, wn = wave & 1;
  const int m0 = blockIdx.y * 128, n0 = blockIdx.x * 128;

  floatx4 acc[4][4] = {};

  for (int k0 = 0; k0 < K; k0 += 32) {
    for (int p = 0; p < 2; p++) {
      int i = p * 256 + wave * 64 + lane;
      int row = i >> 2, c = i & 3;
      gload_lds16(A  + (size_t)(m0 + row) * K + k0 + c * 8,
                  As + (size_t)(p * 256 + wave * 64) * 8);
      gload_lds16(BT + (size_t)(n0 + row) * K + k0 + c * 8,
                  Bs + (size_t)(p * 256 + wave * 64) * 8);
    }
    __syncthreads();

    short8 af[4], bfr[4];
    for (int f = 0; f < 4; f++) {
      af[f]  = *(const short8*)(As + (wm * 64 + f * 16 + l16) * 32 + quad * 8);
      bfr[f] = *(const short8*)(Bs + (wn * 64 + f * 16 + l16) * 32 + quad * 8);
    }
    for (int fm = 0; fm < 4; fm++)
      for (int fn = 0; fn < 4; fn++)
        acc[fm][fn] = mfma_bf16(af[fm], bfr[fn], acc[fm][fn]);
    __syncthreads();
  }

  for (int fm = 0; fm < 4; fm++)
    for (int fn = 0; fn < 4; fn++)
      for (int r = 0; r < 4; r++) {
        int gm = m0 + wm * 64 + fm * 16 + quad * 4 + r;
        int gn = n0 + wn * 64 + fn * 16 + l16;
        float val = acc[fm][fn][r] * scale;
        if (MODE == 0) {
          int b = gm >> 11, s = gm & 2047;
          int h = gn >> 6,  d = gn & 63;
          ((unsigned short*)Cout)[((size_t)((b * H_ + h) * S_ + s) << 6) + d] = f2bf(val);
        } else if (MODE == 1) {
          ((float*)Cout)[((size_t)gm << 10) + gn] = val;
        } else {
          int b = gm >> 11, s = gm & 2047;
          int h = gn >> 6,  d = gn & 63;
          int p = ((s & 63) >> 4) + (s & 15) * 4;   // inv_sigma within 64-block
          ((unsigned short*)Cout)[(((size_t)(b * H_ + h) * 64 + d) << 11) + (s & ~63) + p] = f2bf(val);
        }
      }
}

// ---------------------------------------------------------------------------
// Flash attention v3: no-max exp2 softmax, V pre-transposed+sigma-permuted in
// global ([B,H,64,S]), both K and V^T staged via XOR-swizzled global_load_lds,
// l computed by MFMA against a ones-column B-frag (sums the SAME truncated P
// as PV -> normalization exact).
//
// Occupancy restructure vs previous version: 512-thread / 8-wave blocks, each
// wave owns 32 q rows (2 qt of 16) instead of 64. Same grid (8,64) -> still
// 2 blocks/CU, but 16 waves/CU = 4 waves/SIMD (was 2): the per-qt dependency
// chain (QK MFMA -> exp2 -> pack -> ds_write -> ds_read -> PV MFMA) is now
// hidden by cross-wave overlap. K/V global->LDS traffic unchanged (one 8 KB
// tile per WG per j-iter, staged by 512 lanes in a single pass).
//
// XCD swizzle: dispatch linear id % 8 == blockIdx.x, so use blockIdx.x as the
// head-group selector -> the 8 q-chunk blocks of one head share one XCD's L2
// (K+V per head = 512 KB; was spread across all 8 XCDs before).
// ---------------------------------------------------------------------------
__global__ __launch_bounds__(512, 4) void attn_kernel(const unsigned short* __restrict__ q,
                                                      const unsigned short* __restrict__ k,
                                                      const unsigned short* __restrict__ vT,
                                                      unsigned short* __restrict__ X) {
  __shared__ unsigned short Ks[64 * 64];      // 8 KB, XOR-swizzled chunks
  __shared__ unsigned short Vt[64 * 64];      // 8 KB, XOR-swizzled chunks
  __shared__ unsigned short Ps[8][16 * 72];   // 18 KB, per-wave P tile, padded

  const int tid  = threadIdx.x;
  const int wave = tid >> 6, lane = tid & 63;
  const int quad = lane >> 4, l16 = lane & 15;
  // XCD-aware remap (bijective on 8x64 grid)
  const int bh = blockIdx.x * 8 + (blockIdx.y >> 3);
  const int q0 = (blockIdx.y & 7) * 256;

  const unsigned short* qh = q  + (size_t)bh * S_ * 64;
  const unsigned short* kh = k  + (size_t)bh * S_ * 64;
  const unsigned short* vh = vT + (size_t)bh * 64 * S_;   // [d][s']

  // Q fragments (A-layout), resident: 2 qt x 2 k-chunks
  short8 qf[2][2];
  for (int qt = 0; qt < 2; qt++) {
    int row = q0 + wave * 32 + qt * 16 + l16;
    for (int kk = 0; kk < 2; kk++)
      qf[qt][kk] = *(const short8*)(qh + (size_t)row * 64 + kk * 32 + quad * 8);
  }

  // ones-column B-frag: B[k][n] = (n==0) ? 1 : 0
  short8 onesb = {};
  if (l16 == 0)
    for (int e = 0; e < 8; e++) onesb[e] = (short)0x3F80;

  floatx4 O[2][4] = {};
  floatx4 lacc[2] = {};

  for (int j0 = 0; j0 < S_; j0 += 64) {
    __syncthreads();   // prior iter's frag reads complete before overwrite

    // stage K and V^T tiles: async 16B/lane, chunk c of row r at slot c^(r&7)
    // 512 lanes x 16B = full 8 KB tile in one pass
    {
      int r  = tid >> 3;
      int gc = (tid & 7) ^ (r & 7);
      gload_lds16(kh + (size_t)(j0 + r) * 64 + gc * 8,
                  Ks + (size_t)(wave * 64) * 8);
      gload_lds16(vh + (size_t)r * S_ + j0 + gc * 8,
                  Vt + (size_t)(wave * 64) * 8);
    }
    __syncthreads();

    // K frags (B-layout: n=j=jf*16+l16, k=d): undo swizzle
    short8 kf[4][2];
    for (int jf = 0; jf < 4; jf++)
      for (int kk = 0; kk < 2; kk++) {
        int sl = (kk * 4 + quad) ^ (l16 & 7);
        kf[jf][kk] = *(const short8*)(Ks + (jf * 16 + l16) * 64 + sl * 8);
      }

    unsigned short* pw = Ps[wave];
    short8 pa[2][2];
    for (int qt = 0; qt < 2; qt++) {
      floatx4 s[4] = {};
      for (int jf = 0; jf < 4; jf++) {
        s[jf] = mfma_bf16(qf[qt][0], kf[jf][0], s[jf]);
        s[jf] = mfma_bf16(qf[qt][1], kf[jf][1], s[jf]);
      }
      // p = exp2(score) (q pre-scaled by log2e/sqrt(dk)); RTZ-pack to bf16.
      // Lane's 4 jf-values land at consecutive sigma positions 4*l16+jf.
      for (int r = 0; r < 4; r++) {
        float e0 = exp2f(s[0][r]), e1 = exp2f(s[1][r]);
        float e2 = exp2f(s[2][r]), e3 = exp2f(s[3][r]);
        uint2 pk;
        pk.x = pack_bf2(e0, e1);
        pk.y = pack_bf2(e2, e3);
        *(uint2*)(pw + (quad * 4 + r) * 72 + l16 * 4) = pk;
      }
      pa[qt][0] = *(const short8*)(pw + l16 * 72 + quad * 8);
      pa[qt][1] = *(const short8*)(pw + l16 * 72 + 32 + quad * 8);
      lacc[qt] = mfma_bf16(pa[qt][0], onesb, lacc[qt]);
      lacc[qt] = mfma_bf16(pa[qt][1], onesb, lacc[qt]);
    }

    // PV: V frags loaded per-df (8 VGPRs live at a time, keeps pressure <128)
    for (int df = 0; df < 4; df++) {
      int sl0 = quad ^ (l16 & 7);
      int sl1 = (4 + quad) ^ (l16 & 7);
      short8 v0 = *(const short8*)(Vt + (df * 16 + l16) * 64 + sl0 * 8);
      short8 v1 = *(const short8*)(Vt + (df * 16 + l16) * 64 + sl1 * 8);
      for (int qt = 0; qt < 2; qt++) {
        O[qt][df] = mfma_bf16(pa[qt][0], v0, O[qt][df]);
        O[qt][df] = mfma_bf16(pa[qt][1], v1, O[qt][df]);
      }
    }
  }

  // epilogue: l lives in lane quad*16 (col 0), reg r; broadcast, divide, store
  const int b = bh >> 4, h = bh & 15;
  for (int qt = 0; qt < 2; qt++)
    for (int r = 0; r < 4; r++) {
      float lsum = __shfl(lacc[qt][r], (lane & 48));
      float inv = 1.0f / lsum;
      int row = q0 + wave * 32 + qt * 16 + quad * 4 + r;
      unsigned short* dst = X + ((size_t)(b * S_ + row) << 10) + h * 64;
      for (int df = 0; df < 4; df++)
        dst[df * 16 + l16] = f2bf(O[qt][df][r] * inv);
    }
}

// ---------------------------------------------------------------------------
extern "C" void kernel_launch(void* const* d_in, const int* in_sizes, int n_in,
                              void* d_out, int out_size, void* d_ws, size_t ws_size,
                              hipStream_t stream) {
  const float* Q  = (const float*)d_in[0];
  const float* K  = (const float*)d_in[1];
  const float* V  = (const float*)d_in[2];
  const float* wq = (const float*)d_in[3];
  const float* wk = (const float*)d_in[4];
  const float* wv = (const float*)d_in[5];
  const float* wo = (const float*)d_in[6];

  char* ws = (char*)d_ws;
  unsigned short* buf0 = (unsigned short*)ws;                        // 16 MB
  unsigned short* wqT  = (unsigned short*)(ws + (size_t)(16 << 20));
  unsigned short* wkT  = (unsigned short*)(ws + (size_t)(18 << 20));
  unsigned short* wvT  = (unsigned short*)(ws + (size_t)(20 << 20));
  unsigned short* woT  = (unsigned short*)(ws + (size_t)(22 << 20));
  unsigned short* qP   = (unsigned short*)(ws + (size_t)(24 << 20));  // [B,H,S,64]
  unsigned short* kP   = (unsigned short*)(ws + (size_t)(40 << 20));  // [B,H,S,64]
  unsigned short* vTg  = (unsigned short*)(ws + (size_t)(56 << 20));  // [B,H,64,S] sigma

  const int n4 = NTOK * DM_ / 4;
  const float SC = 0.18033688011112043f;   // log2(e) / sqrt(64), folded into q

  wt_kernel<<<dim3(16, 16, 4), dim3(256), 0, stream>>>(wq, wk, wv, wo, wqT, wkT, wvT, woT);

  cast_bf16_kernel<<<dim3(8192), dim3(256), 0, stream>>>(Q, buf0, n4);
  gemm_bt_kernel<0><<<dim3(8, 64), dim3(256), 0, stream>>>(buf0, wqT, qP, SC);
  cast_bf16_kernel<<<dim3(8192), dim3(256), 0, stream>>>(K, buf0, n4);
  gemm_bt_kernel<0><<<dim3(8, 64), dim3(256), 0, stream>>>(buf0, wkT, kP, 1.0f);
  cast_bf16_kernel<<<dim3(8192), dim3(256), 0, stream>>>(V, buf0, n4);
  gemm_bt_kernel<2><<<dim3(8, 64), dim3(256), 0, stream>>>(buf0, wvT, vTg, 1.0f);

  attn_kernel<<<dim3(8, 64), dim3(512), 0, stream>>>(qP, kP, vTg, buf0);

  gemm_bt_kernel<1><<<dim3(8, 64), dim3(256), 0, stream>>>(buf0, woT, (float*)d_out, 1.0f);
}

// Round 2
// 340.701 us; speedup vs baseline: 1.1087x; 1.0909x over previous
//
#include <hip/hip_runtime.h>
#include <stdint.h>

// Problem constants
#define B_   4
#define S_   2048
#define H_   16
#define D_   64
#define DM_  1024
#define NTOK (B_ * S_)          // 8192 tokens

typedef __attribute__((ext_vector_type(8))) short short8;   // 8 bf16 (4 VGPRs)
typedef __attribute__((ext_vector_type(4))) float floatx4;  // MFMA C/D

__device__ inline unsigned short f2bf(float f) {
  // RNE float -> bf16 (finite inputs)
  unsigned int u = __float_as_uint(f);
  u += 0x7FFFu + ((u >> 16) & 1u);
  return (unsigned short)(u >> 16);
}

__device__ inline floatx4 mfma_bf16(short8 a, short8 b, floatx4 c) {
  return __builtin_amdgcn_mfma_f32_16x16x32_bf16(a, b, c, 0, 0, 0);
}

// pack two fp32 into bf16x2 (RTZ: take high 16 bits of each) — one v_perm_b32
__device__ inline unsigned int pack_bf2(float lo, float hi) {
  return __builtin_amdgcn_perm(__float_as_uint(hi), __float_as_uint(lo), 0x07060302u);
}

// async global->LDS, 16B per lane; LDS dest = wave-uniform base + lane*16
__device__ inline void gload_lds16(const unsigned short* g, unsigned short* l) {
  __builtin_amdgcn_global_load_lds(
      (const __attribute__((address_space(1))) unsigned int*)g,
      (__attribute__((address_space(3))) unsigned int*)l, 16, 0, 0);
}

// ---------------------------------------------------------------------------
// fp32 -> bf16 bulk cast
// ---------------------------------------------------------------------------
__global__ __launch_bounds__(256) void cast_bf16_kernel(const float* __restrict__ in,
                                                        unsigned short* __restrict__ out,
                                                        int n4) {
  int i = blockIdx.x * 256 + threadIdx.x;
  if (i < n4) {
    float4 v = ((const float4*)in)[i];
    ushort4 o;
    o.x = f2bf(v.x); o.y = f2bf(v.y); o.z = f2bf(v.z); o.w = f2bf(v.w);
    ((ushort4*)out)[i] = o;
  }
}

// ---------------------------------------------------------------------------
// LDS-tiled weight cast+transpose: w[k][n] fp32 [1024x1024] -> wT[n][k] bf16.
// ---------------------------------------------------------------------------
__global__ __launch_bounds__(256) void wt_kernel(const float* __restrict__ w0,
                                                 const float* __restrict__ w1,
                                                 const float* __restrict__ w2,
                                                 const float* __restrict__ w3,
                                                 unsigned short* __restrict__ o0,
                                                 unsigned short* __restrict__ o1,
                                                 unsigned short* __restrict__ o2,
                                                 unsigned short* __restrict__ o3) {
  __shared__ unsigned short T[64 * 68];   // transposed tile [n][k], stride 68
  const float* w = blockIdx.z == 0 ? w0 : blockIdx.z == 1 ? w1 : blockIdx.z == 2 ? w2 : w3;
  unsigned short* o = blockIdx.z == 0 ? o0 : blockIdx.z == 1 ? o1 : blockIdx.z == 2 ? o2 : o3;
  const int tid = threadIdx.x;
  const int R0 = blockIdx.y * 64;   // k-block
  const int C0 = blockIdx.x * 64;   // n-block
  for (int it = 0; it < 16; it++) {
    int lr = it * 4 + (tid >> 6), lc = tid & 63;
    T[lc * 68 + lr] = f2bf(w[(size_t)(R0 + lr) * 1024 + C0 + lc]);
  }
  __syncthreads();
  for (int it = 0; it < 2; it++) {
    int orow = it * 32 + (tid >> 3), oc = (tid & 7) * 8;
    union { ushort4 h[2]; short8 v8; } u;
    u.h[0] = *(const ushort4*)(T + orow * 68 + oc);
    u.h[1] = *(const ushort4*)(T + orow * 68 + oc + 4);
    *(short8*)(o + (size_t)(C0 + orow) * 1024 + R0 + oc) = u.v8;
  }
}

// ---------------------------------------------------------------------------
// bf16 GEMM (m97 structure): C[8192,1024] = A[8192,1024] x BT[1024,1024]^T
// MODE 0: scale + bf16 scatter into [B,H,S,64]
// MODE 1: fp32 row-major
// MODE 2: bf16 scatter into V^T layout [B,H,64,S] with per-64-block sigma perm
//
// XCD swizzle: dispatch linear id%8 == blockIdx.x (grid x=8). Remap so each
// XCD owns 8 consecutive A-panels (8 x 256KB = 2MB, fits its 4MB L2) and
// iterates all 8 B-blocks against them -> A fetched once per XCD instead of
// 8x (one fetch per XCD-scattered n-block).
// ---------------------------------------------------------------------------
template <int MODE>
__global__ __launch_bounds__(256) void gemm_bt_kernel(const unsigned short* __restrict__ A,
                                                      const unsigned short* __restrict__ BT,
                                                      void* __restrict__ Cout,
                                                      float scale) {
  constexpr int K = 1024;
  __shared__ unsigned short As[128 * 32];  // 8 KB, slot i (16B) = chunk i row-major
  __shared__ unsigned short Bs[128 * 32];  // 8 KB

  const int tid  = threadIdx.x;
  const int wave = tid >> 6, lane = tid & 63;
  const int quad = lane >> 4, l16 = lane & 15;
  const int wm = wave >> 1, wn = wave & 1;
  // XCD-aware remap (bijective on 8x64 grid)
  const int mb = blockIdx.x * 8 + (blockIdx.y >> 3);   // 0..63
  const int nb = blockIdx.y & 7;                        // 0..7
  const int m0 = mb * 128, n0 = nb * 128;

  floatx4 acc[4][4] = {};

  for (int k0 = 0; k0 < K; k0 += 32) {
    for (int p = 0; p < 2; p++) {
      int i = p * 256 + wave * 64 + lane;
      int row = i >> 2, c = i & 3;
      gload_lds16(A  + (size_t)(m0 + row) * K + k0 + c * 8,
                  As + (size_t)(p * 256 + wave * 64) * 8);
      gload_lds16(BT + (size_t)(n0 + row) * K + k0 + c * 8,
                  Bs + (size_t)(p * 256 + wave * 64) * 8);
    }
    __syncthreads();

    short8 af[4], bfr[4];
    for (int f = 0; f < 4; f++) {
      af[f]  = *(const short8*)(As + (wm * 64 + f * 16 + l16) * 32 + quad * 8);
      bfr[f] = *(const short8*)(Bs + (wn * 64 + f * 16 + l16) * 32 + quad * 8);
    }
    for (int fm = 0; fm < 4; fm++)
      for (int fn = 0; fn < 4; fn++)
        acc[fm][fn] = mfma_bf16(af[fm], bfr[fn], acc[fm][fn]);
    __syncthreads();
  }

  for (int fm = 0; fm < 4; fm++)
    for (int fn = 0; fn < 4; fn++)
      for (int r = 0; r < 4; r++) {
        int gm = m0 + wm * 64 + fm * 16 + quad * 4 + r;
        int gn = n0 + wn * 64 + fn * 16 + l16;
        float val = acc[fm][fn][r] * scale;
        if (MODE == 0) {
          int b = gm >> 11, s = gm & 2047;
          int h = gn >> 6,  d = gn & 63;
          ((unsigned short*)Cout)[((size_t)((b * H_ + h) * S_ + s) << 6) + d] = f2bf(val);
        } else if (MODE == 1) {
          ((float*)Cout)[((size_t)gm << 10) + gn] = val;
        } else {
          int b = gm >> 11, s = gm & 2047;
          int h = gn >> 6,  d = gn & 63;
          int p = ((s & 63) >> 4) + (s & 15) * 4;   // inv_sigma within 64-block
          ((unsigned short*)Cout)[(((size_t)(b * H_ + h) * 64 + d) << 11) + (s & ~63) + p] = f2bf(val);
        }
      }
}

// ---------------------------------------------------------------------------
// Flash attention v4: no-max exp2 softmax, V pre-transposed+sigma-permuted
// ([B,H,64,S]), K and V^T staged via XOR-swizzled global_load_lds.
//
// Changes vs v3 (counters: VALUBusy 60 + MfmaUtil 30 ~= issue-saturated,
// stage->drain->barrier exposed load latency every iter):
//  - Double-buffered K/V LDS, ONE barrier per iter: next tile's loads are
//    issued right after the barrier and drain at the NEXT barrier, after the
//    whole compute phase has covered their latency (T3-lite, no inline asm —
//    relies on __syncthreads' vmcnt(0)+lgkmcnt(0) drain for correctness).
//  - exp2 via raw v_exp_f32 (__builtin_amdgcn_exp2f): drops ocml's
//    denorm-fixup VALU ops; denormal tails flush to 0 which is exactly what
//    softmax wants, and l sums the same truncated p (normalization exact).
//  - s[] accumulator init from a hoisted zero (kills 32 v_mov per iter).
// ---------------------------------------------------------------------------
__global__ __launch_bounds__(512, 4) void attn_kernel(const unsigned short* __restrict__ q,
                                                      const unsigned short* __restrict__ k,
                                                      const unsigned short* __restrict__ vT,
                                                      unsigned short* __restrict__ X) {
  __shared__ unsigned short Ks[2][64 * 64];   // 2 x 8 KB, XOR-swizzled chunks
  __shared__ unsigned short Vt[2][64 * 64];   // 2 x 8 KB, XOR-swizzled chunks
  __shared__ unsigned short Ps[8][16 * 72];   // 18 KB, per-wave P tile, padded

  const int tid  = threadIdx.x;
  const int wave = tid >> 6, lane = tid & 63;
  const int quad = lane >> 4, l16 = lane & 15;
  // XCD-aware remap (bijective on 8x64 grid)
  const int bh = blockIdx.x * 8 + (blockIdx.y >> 3);
  const int q0 = (blockIdx.y & 7) * 256;

  const unsigned short* qh = q  + (size_t)bh * S_ * 64;
  const unsigned short* kh = k  + (size_t)bh * S_ * 64;
  const unsigned short* vh = vT + (size_t)bh * 64 * S_;   // [d][s']

  // staging pattern: 512 lanes x 16B = full 8 KB tile; chunk c of row r at
  // slot c^(r&7)
  const int sr  = tid >> 3;
  const int sgc = (tid & 7) ^ (sr & 7);

  // Q fragments (A-layout), resident: 2 qt x 2 k-chunks
  short8 qf[2][2];
  for (int qt = 0; qt < 2; qt++) {
    int row = q0 + wave * 32 + qt * 16 + l16;
    for (int kk = 0; kk < 2; kk++)
      qf[qt][kk] = *(const short8*)(qh + (size_t)row * 64 + kk * 32 + quad * 8);
  }

  // ones-column B-frag: B[k][n] = (n==0) ? 1 : 0
  short8 onesb = {};
  if (l16 == 0)
    for (int e = 0; e < 8; e++) onesb[e] = (short)0x3F80;

  const floatx4 fz = {};   // hoisted zero for per-iter score accumulators
  floatx4 O[2][4] = {};
  floatx4 lacc[2] = {};

  // prologue: stage tile 0 into buffer 0
  gload_lds16(kh + (size_t)sr * 64 + sgc * 8,       Ks[0] + (size_t)(wave * 64) * 8);
  gload_lds16(vh + (size_t)sr * S_ + 0 + sgc * 8,   Vt[0] + (size_t)(wave * 64) * 8);

  int cur = 0;
  for (int j0 = 0; j0 < S_; j0 += 64) {
    // One barrier per iter. Compiler-emitted vmcnt(0) drain here covers the
    // loads issued LAST iter (full compute phase in flight -> cheap) and
    // guarantees buf[cur] is fully staged chip-wide; also orders all waves'
    // reads of buf[cur^1] before we overwrite it below.
    __syncthreads();

    // issue next tile's stage early (overlaps with this iter's compute)
    if (j0 + 64 < S_) {
      int nxt = cur ^ 1;
      gload_lds16(kh + (size_t)(j0 + 64 + sr) * 64 + sgc * 8,
                  Ks[nxt] + (size_t)(wave * 64) * 8);
      gload_lds16(vh + (size_t)sr * S_ + (j0 + 64) + sgc * 8,
                  Vt[nxt] + (size_t)(wave * 64) * 8);
    }

    // K frags (B-layout: n=j=jf*16+l16, k=d): undo swizzle
    short8 kf[4][2];
    for (int jf = 0; jf < 4; jf++)
      for (int kk = 0; kk < 2; kk++) {
        int sl = (kk * 4 + quad) ^ (l16 & 7);
        kf[jf][kk] = *(const short8*)(Ks[cur] + (jf * 16 + l16) * 64 + sl * 8);
      }

    unsigned short* pw = Ps[wave];
    short8 pa[2][2];
    for (int qt = 0; qt < 2; qt++) {
      floatx4 s[4];
      for (int jf = 0; jf < 4; jf++) {
        s[jf] = mfma_bf16(qf[qt][0], kf[jf][0], fz);
        s[jf] = mfma_bf16(qf[qt][1], kf[jf][1], s[jf]);
      }
      // p = exp2(score) (q pre-scaled by log2e/sqrt(dk)); raw v_exp_f32,
      // RTZ-pack to bf16. Lane's 4 jf-values land at sigma positions 4*l16+jf.
      for (int r = 0; r < 4; r++) {
        float e0 = __builtin_amdgcn_exp2f(s[0][r]);
        float e1 = __builtin_amdgcn_exp2f(s[1][r]);
        float e2 = __builtin_amdgcn_exp2f(s[2][r]);
        float e3 = __builtin_amdgcn_exp2f(s[3][r]);
        uint2 pk;
        pk.x = pack_bf2(e0, e1);
        pk.y = pack_bf2(e2, e3);
        *(uint2*)(pw + (quad * 4 + r) * 72 + l16 * 4) = pk;
      }
      pa[qt][0] = *(const short8*)(pw + l16 * 72 + quad * 8);
      pa[qt][1] = *(const short8*)(pw + l16 * 72 + 32 + quad * 8);
      lacc[qt] = mfma_bf16(pa[qt][0], onesb, lacc[qt]);
      lacc[qt] = mfma_bf16(pa[qt][1], onesb, lacc[qt]);
    }

    // PV: V frags loaded per-df (8 VGPRs live at a time)
    for (int df = 0; df < 4; df++) {
      int sl0 = quad ^ (l16 & 7);
      int sl1 = (4 + quad) ^ (l16 & 7);
      short8 v0 = *(const short8*)(Vt[cur] + (df * 16 + l16) * 64 + sl0 * 8);
      short8 v1 = *(const short8*)(Vt[cur] + (df * 16 + l16) * 64 + sl1 * 8);
      for (int qt = 0; qt < 2; qt++) {
        O[qt][df] = mfma_bf16(pa[qt][0], v0, O[qt][df]);
        O[qt][df] = mfma_bf16(pa[qt][1], v1, O[qt][df]);
      }
    }
    cur ^= 1;
  }

  // epilogue: l lives in lane quad*16 (col 0), reg r; broadcast, divide, store
  const int b = bh >> 4, h = bh & 15;
  for (int qt = 0; qt < 2; qt++)
    for (int r = 0; r < 4; r++) {
      float lsum = __shfl(lacc[qt][r], (lane & 48));
      float inv = 1.0f / lsum;
      int row = q0 + wave * 32 + qt * 16 + quad * 4 + r;
      unsigned short* dst = X + ((size_t)(b * S_ + row) << 10) + h * 64;
      for (int df = 0; df < 4; df++)
        dst[df * 16 + l16] = f2bf(O[qt][df][r] * inv);
    }
}

// ---------------------------------------------------------------------------
extern "C" void kernel_launch(void* const* d_in, const int* in_sizes, int n_in,
                              void* d_out, int out_size, void* d_ws, size_t ws_size,
                              hipStream_t stream) {
  const float* Q  = (const float*)d_in[0];
  const float* K  = (const float*)d_in[1];
  const float* V  = (const float*)d_in[2];
  const float* wq = (const float*)d_in[3];
  const float* wk = (const float*)d_in[4];
  const float* wv = (const float*)d_in[5];
  const float* wo = (const float*)d_in[6];

  char* ws = (char*)d_ws;
  unsigned short* buf0 = (unsigned short*)ws;                        // 16 MB
  unsigned short* wqT  = (unsigned short*)(ws + (size_t)(16 << 20));
  unsigned short* wkT  = (unsigned short*)(ws + (size_t)(18 << 20));
  unsigned short* wvT  = (unsigned short*)(ws + (size_t)(20 << 20));
  unsigned short* woT  = (unsigned short*)(ws + (size_t)(22 << 20));
  unsigned short* qP   = (unsigned short*)(ws + (size_t)(24 << 20));  // [B,H,S,64]
  unsigned short* kP   = (unsigned short*)(ws + (size_t)(40 << 20));  // [B,H,S,64]
  unsigned short* vTg  = (unsigned short*)(ws + (size_t)(56 << 20));  // [B,H,64,S] sigma

  const int n4 = NTOK * DM_ / 4;
  const float SC = 0.18033688011112043f;   // log2(e) / sqrt(64), folded into q

  wt_kernel<<<dim3(16, 16, 4), dim3(256), 0, stream>>>(wq, wk, wv, wo, wqT, wkT, wvT, woT);

  cast_bf16_kernel<<<dim3(8192), dim3(256), 0, stream>>>(Q, buf0, n4);
  gemm_bt_kernel<0><<<dim3(8, 64), dim3(256), 0, stream>>>(buf0, wqT, qP, SC);
  cast_bf16_kernel<<<dim3(8192), dim3(256), 0, stream>>>(K, buf0, n4);
  gemm_bt_kernel<0><<<dim3(8, 64), dim3(256), 0, stream>>>(buf0, wkT, kP, 1.0f);
  cast_bf16_kernel<<<dim3(8192), dim3(256), 0, stream>>>(V, buf0, n4);
  gemm_bt_kernel<2><<<dim3(8, 64), dim3(256), 0, stream>>>(buf0, wvT, vTg, 1.0f);

  attn_kernel<<<dim3(8, 64), dim3(512), 0, stream>>>(qP, kP, vTg, buf0);

  gemm_bt_kernel<1><<<dim3(8, 64), dim3(256), 0, stream>>>(buf0, woT, (float*)d_out, 1.0f);
}